// Round 8
// baseline (35162.122 us; speedup 1.0000x reference)
//
#include <hip/hip_runtime.h>
#include <stdint.h>
#include <math.h>

// Persistent barrier-free 2-layer LSTM rollout, MI355X (gfx950).
// v9 = EXACT v6 structure (best verified: 32.9ms) with ONE change in the
// poll's wait phase:
//   v1/v6/v8 all had ALL 64 LANES of every waiting wave spinning
//   concurrently (~92K coherent reads/us device-wide). Evidence across 8
//   kernels: Lambda is insensitive to read DISTRIBUTION (v8 replication
//   neutral) and write volume (v8), but strongly sensitive to total read
//   RATE (v3 reload-all 2.8x, v7 3-arrays +14%). v9 tests the rate axis
//   directly: ONLY LANE 0 spins (on one far victim slot, (wg+255)&511);
//   the other 63 lanes are exec-masked (wave waits, zero traffic). On
//   sentinel exit, v6's batched refresh + lazy walk verifies ALL 8 slots
//   (correctness interlock identical: poll returns only when every slot
//   carries the tag). Wait-phase read rate drops 64x.
// Numerics bit-identical to v1/v6.
//
// 512 WGs x 64 thr (1 wave); wave w owns h-units {2w, 2w+1} of both layers.
// Critical chain/step: poll h0 -> 8 gate rows -> publish h1 ->
//                      poll h1 -> W2 row -> cell0 -> publish h0.
// Whh0/Whh1 rows + threefry RNG run post-publish (shadow time).

#define H     1024
#define NSTEP 8192
#define NWG   512
#define BLK   64
#define NROW  25   // 0-7 Wih1 (4 gates x 2 units), 8-15 Whh0, 16-23 Whh1, 24 W2

typedef _Float16 h2 __attribute__((ext_vector_type(2)));
typedef _Float16 h8 __attribute__((ext_vector_type(8)));

union U32H2 { uint32_t u; h2 v; };

__device__ __forceinline__ unsigned long long pack_vt(float v0, float v1, uint32_t tag){
  U32H2 p; p.v.x = (_Float16)v0; p.v.y = (_Float16)v1;
  return ((unsigned long long)tag << 32) | (unsigned long long)p.u;
}

// Exact JAX threefry2x32.
__device__ __forceinline__ uint2 tf2x32(uint32_t k0, uint32_t k1, uint32_t x0, uint32_t x1){
  uint32_t k2 = k0 ^ k1 ^ 0x1BD11BDAu;
  x0 += k0; x1 += k1;
#define TFR(r) { x0 += x1; x1 = (x1 << (r)) | (x1 >> (32 - (r))); x1 ^= x0; }
  TFR(13) TFR(15) TFR(26) TFR(6)
  x0 += k1; x1 += k2 + 1u;
  TFR(17) TFR(29) TFR(16) TFR(24)
  x0 += k2; x1 += k0 + 2u;
  TFR(13) TFR(15) TFR(26) TFR(6)
  x0 += k0; x1 += k1 + 3u;
  TFR(17) TFR(29) TFR(16) TFR(24)
  x0 += k1; x1 += k2 + 4u;
  TFR(13) TFR(15) TFR(26) TFR(6)
  x0 += k2; x1 += k0 + 5u;
#undef TFR
  uint2 r; r.x = x0; r.y = x1; return r;
}

// keys = threefry_split(key(42), 8192)
__device__ __forceinline__ uint32_t jax_word(uint32_t i){
  return (i < 8192u) ? tf2x32(0u, 42u, i, i + 8192u).x
                     : tf2x32(0u, 42u, i - 8192u, i).y;
}

__device__ __forceinline__ float wred64(float x){
  #pragma unroll
  for(int off = 32; off > 0; off >>= 1) x += __shfl_xor(x, off, 64);
  return x;
}

#if __has_builtin(__builtin_amdgcn_fdot2)
__device__ __forceinline__ float fdot2f(h2 a, h2 b, float c){ return __builtin_amdgcn_fdot2(a, b, c, false); }
#else
__device__ __forceinline__ float fdot2f(h2 a, h2 b, float c){
  return (float)a.x * (float)b.x + (float)a.y * (float)b.y + c;
}
#endif

__device__ __forceinline__ float sigm(float x){
  x = fminf(fmaxf(x, -30.f), 30.f);
  return 1.f / (1.f + __expf(-x));
}
__device__ __forceinline__ float tanh_f(float x){
  x = fminf(fmaxf(x, -15.f), 15.f);
  float e = __expf(2.f * x);
  return (e - 1.f) / (e + 1.f);
}

__device__ __forceinline__ unsigned long long ld_slot(const unsigned long long* p){
  return __hip_atomic_load((unsigned long long*)p, __ATOMIC_RELAXED, __HIP_MEMORY_SCOPE_AGENT);
}

// Poll this lane's 8 slots (fragment pairs [4l,4l+4) and [256+4l,+4)).
// phase 0: batched initial snapshot (issued before the wait; results land
//          during it)
// phase 1: SINGLE-LANE sentinel spin — only lane 0 reloads (one far victim
//          slot); the other 63 lanes are exec-masked off (zero traffic)
// phase 2: one batched concurrent reload of all stale slots (~1 LLC RT)
// phase 3: lazy per-slot walk for rare stragglers (verifies ALL 8 slots)
__device__ __forceinline__ void poll_h(const unsigned long long* __restrict__ buf,
                                       uint32_t tag, int lane, int victim, h2* hv){
  const unsigned long long* p0 = buf + (lane << 2);
  const unsigned long long* p1 = buf + 256 + (lane << 2);
  unsigned long long pv[8];
  #pragma unroll
  for(int k = 0; k < 4; k++) pv[k]     = ld_slot(p0 + k);
  #pragma unroll
  for(int k = 0; k < 4; k++) pv[4 + k] = ld_slot(p1 + k);

  // phase 1: lane-0-only sentinel spin on the victim slot
  if(lane == 0){
    const unsigned long long* vs = buf + victim;
    unsigned long long v = ld_slot(vs);
    while((uint32_t)(v >> 32) != tag){
      __builtin_amdgcn_s_sleep(1);
      v = ld_slot(vs);
    }
  }
  // exec reconverges here: whole wave waited at 1-lane read rate

  // phase 2: batched refresh of whatever is still stale
  bool any = false;
  #pragma unroll
  for(int k = 0; k < 8; k++) any |= ((uint32_t)(pv[k] >> 32) != tag);
  if(any){
    #pragma unroll
    for(int k = 0; k < 8; k++){
      if((uint32_t)(pv[k] >> 32) != tag){
        const unsigned long long* p = (k < 4) ? (p0 + k) : (p1 + (k - 4));
        pv[k] = ld_slot(p);
      }
    }
    // phase 3: stragglers (rare) — lazy walk; verifies every slot
    #pragma unroll
    for(int k = 0; k < 8; k++){
      const unsigned long long* p = (k < 4) ? (p0 + k) : (p1 + (k - 4));
      while((uint32_t)(pv[k] >> 32) != tag){
        __builtin_amdgcn_s_sleep(1);
        pv[k] = ld_slot(p);
      }
    }
  }

  #pragma unroll
  for(int k = 0; k < 8; k++){
    U32H2 u; u.u = (uint32_t)pv[k];
    hv[k] = u.v;
  }
}

// Row dot partial: lane l covers h2 [4l,4l+4) and [256+4l,+4): two b128
// LDS reads, lane stride 16B -> conflict-free.
__device__ __forceinline__ float row_part(const h2* __restrict__ wrow, int lane, const h2* hv){
  h8 wl = *(const h8*)(wrow + (lane << 2));
  h8 wh = *(const h8*)(wrow + 256 + (lane << 2));
  float a0 = 0.f, a1 = 0.f;
  h2 w;
  w = __builtin_shufflevector(wl, wl, 0, 1); a0 = fdot2f(w, hv[0], a0);
  w = __builtin_shufflevector(wl, wl, 2, 3); a1 = fdot2f(w, hv[1], a1);
  w = __builtin_shufflevector(wl, wl, 4, 5); a0 = fdot2f(w, hv[2], a0);
  w = __builtin_shufflevector(wl, wl, 6, 7); a1 = fdot2f(w, hv[3], a1);
  w = __builtin_shufflevector(wh, wh, 0, 1); a0 = fdot2f(w, hv[4], a0);
  w = __builtin_shufflevector(wh, wh, 2, 3); a1 = fdot2f(w, hv[5], a1);
  w = __builtin_shufflevector(wh, wh, 4, 5); a0 = fdot2f(w, hv[6], a0);
  w = __builtin_shufflevector(wh, wh, 6, 7); a1 = fdot2f(w, hv[7], a1);
  return a0 + a1;
}

__global__ void __launch_bounds__(BLK)
lstm_persist(const float* __restrict__ ctx,  const float* __restrict__ W1p,  const float* __restrict__ b1p,
             const float* __restrict__ Wih0, const float* __restrict__ Whh0,
             const float* __restrict__ bih0, const float* __restrict__ bhh0,
             const float* __restrict__ Wih1, const float* __restrict__ Whh1,
             const float* __restrict__ bih1, const float* __restrict__ bhh1,
             const float* __restrict__ W2p,  const float* __restrict__ b2p,
             float* __restrict__ out,
             unsigned long long* __restrict__ h0buf,
             unsigned long long* __restrict__ h1buf)
{
  __shared__ h2 w[NROW][H/2];   // 51.2 KB (<64KB/block cap); 2 WGs/CU

  const int lane = threadIdx.x;   // single wave per WG
  const int wg   = blockIdx.x;
  const int j0   = wg << 1;       // this wave's two h-units: j0, j0+1
  const int victim = (wg + 255) & (NWG - 1);   // far sentinel slot

  // ---- one-time: stage 25 rows as f16 (coalesced float4 reads)
  #pragma unroll 1
  for(int r = 0; r < NROW; r++){
    const float* rowp;
    if(r < 8)      { int g = r & 3,        j = j0 + (r >> 2);        rowp = Wih1 + (size_t)(g*H + j)*H; }
    else if(r < 16){ int rr = r - 8;  int g = rr & 3, j = j0 + (rr >> 2); rowp = Whh0 + (size_t)(g*H + j)*H; }
    else if(r < 24){ int rr = r - 16; int g = rr & 3, j = j0 + (rr >> 2); rowp = Whh1 + (size_t)(g*H + j)*H; }
    else           rowp = W2p;
    const float4* s4 = (const float4*)rowp;
    #pragma unroll
    for(int it = 0; it < 4; it++){
      float4 f = s4[lane + (it << 6)];
      h2 pa; pa.x = (_Float16)f.x; pa.y = (_Float16)f.y;
      h2 pb; pb.x = (_Float16)f.z; pb.y = (_Float16)f.w;
      const int ci = (lane + (it << 6)) << 1;
      w[r][ci] = pa; w[r][ci + 1] = pb;
    }
  }
  __syncthreads();

  // per-wave scalars for both units (uniform across lanes)
  float b0g[8], b1g[8], w0g[8];
  #pragma unroll
  for(int e = 0; e < 2; e++){
    const int j = j0 + e;
    #pragma unroll
    for(int g = 0; g < 4; g++){
      b0g[4*e + g] = bih0[g*H + j] + bhh0[g*H + j];
      b1g[4*e + g] = bih1[g*H + j] + bhh1[g*H + j];
      w0g[4*e + g] = Wih0[g*H + j];
    }
  }
  const float b2v = b2p[0];

  // x0 = W1 @ context + b1
  float xacc = 0.f;
  for(int c = lane; c < 512; c += 64) xacc += W1p[c] * ctx[c];
  const float x0 = wred64(xacc) + b1p[0];

  float c0[2], c1[2] = {0.f, 0.f}, logp = 0.f;
  float a0[8];
  float a1[8] = {0.f,0.f,0.f,0.f,0.f,0.f,0.f,0.f};

  // h0(0) from x0 for both units
  {
    float h0v[2];
    #pragma unroll
    for(int e = 0; e < 2; e++){
      float gi = sigm (w0g[4*e+0]*x0 + b0g[4*e+0]);
      float gg = tanh_f(w0g[4*e+2]*x0 + b0g[4*e+2]);
      float go = sigm (w0g[4*e+3]*x0 + b0g[4*e+3]);
      c0[e] = gi * gg;
      h0v[e] = go * tanh_f(c0[e]);
    }
    if(lane == 0)
      __hip_atomic_store(&h0buf[wg], pack_vt(h0v[0], h0v[1], 1u),
                         __ATOMIC_RELAXED, __HIP_MEMORY_SCOPE_AGENT);
  }

  h2 hv[8];
  float u = 0.f;

  #pragma unroll 1
  for(int t = 0; t < NSTEP; t++){
    const uint32_t tt = (uint32_t)t;

    // ================= P1: consume h0(t) =================
    poll_h(h0buf, tt + 1u, lane, victim, hv);

    // critical: 8 layer-1 gate rows (Wih1, both units)
    float s1[8];
    #pragma unroll
    for(int r = 0; r < 8; r++) s1[r] = row_part(&w[r][0], lane, hv);
    #pragma unroll
    for(int off = 32; off > 0; off >>= 1){
      #pragma unroll
      for(int r = 0; r < 8; r++) s1[r] += __shfl_xor(s1[r], off, 64);
    }
    {
      float h1v[2];
      #pragma unroll
      for(int e = 0; e < 2; e++){
        float gi = sigm (s1[4*e+0] + a1[4*e+0] + b1g[4*e+0]);
        float gf = sigm (s1[4*e+1] + a1[4*e+1] + b1g[4*e+1]);
        float gg = tanh_f(s1[4*e+2] + a1[4*e+2] + b1g[4*e+2]);
        float go = sigm (s1[4*e+3] + a1[4*e+3] + b1g[4*e+3]);
        c1[e] = gf*c1[e] + gi*gg;
        h1v[e] = go * tanh_f(c1[e]);
      }
      if(lane == 0)
        __hip_atomic_store(&h1buf[wg], pack_vt(h1v[0], h1v[1], tt + 1u),
                           __ATOMIC_RELAXED, __HIP_MEMORY_SCOPE_AGENT);
    }

    // shadow: RNG + 8 Whh0 rows (a0 for P2's cell0)
    {
      const uint32_t kk0 = jax_word(2u*tt), kk1 = jax_word(2u*tt + 1u);
      const uint32_t bits = tf2x32(kk0, kk1, 0u, 0u).x;
      u = __uint_as_float((bits >> 9) | 0x3f800000u) - 1.0f;
    }
    float sa[8];
    #pragma unroll
    for(int r = 0; r < 8; r++) sa[r] = row_part(&w[8 + r][0], lane, hv);
    #pragma unroll
    for(int off = 32; off > 0; off >>= 1){
      #pragma unroll
      for(int r = 0; r < 8; r++) sa[r] += __shfl_xor(sa[r], off, 64);
    }
    #pragma unroll
    for(int r = 0; r < 8; r++) a0[r] = sa[r];

    // ================= P2: consume h1(t) =================
    poll_h(h1buf, tt + 1u, lane, victim, hv);

    // critical: W2 row -> p,s -> cell0 -> publish h0(t+1)
    float z = row_part(&w[24][0], lane, hv);
    z = wred64(z) + b2v;
    const float p = sigm(z);
    const float s = (u < p) ? 1.f : 0.f;
    {
      float h0v[2];
      #pragma unroll
      for(int e = 0; e < 2; e++){
        float gi = sigm (a0[4*e+0] + w0g[4*e+0]*s + b0g[4*e+0]);
        float gf = sigm (a0[4*e+1] + w0g[4*e+1]*s + b0g[4*e+1]);
        float gg = tanh_f(a0[4*e+2] + w0g[4*e+2]*s + b0g[4*e+2]);
        float go = sigm (a0[4*e+3] + w0g[4*e+3]*s + b0g[4*e+3]);
        c0[e] = gf*c0[e] + gi*gg;
        h0v[e] = go * tanh_f(c0[e]);
      }
      if(lane == 0)
        __hip_atomic_store(&h0buf[wg], pack_vt(h0v[0], h0v[1], tt + 2u),
                           __ATOMIC_RELAXED, __HIP_MEMORY_SCOPE_AGENT);
    }

    // off critical path: logp/out after the publish
    logp += s * __logf(p) + (1.f - s) * __logf(1.f - p);
    if(wg == 0 && lane == 0) out[t] = s;

    // shadow: 8 Whh1 rows (a1 for next step's P1)
    float sb[8];
    #pragma unroll
    for(int r = 0; r < 8; r++) sb[r] = row_part(&w[16 + r][0], lane, hv);
    #pragma unroll
    for(int off = 32; off > 0; off >>= 1){
      #pragma unroll
      for(int r = 0; r < 8; r++) sb[r] += __shfl_xor(sb[r], off, 64);
    }
    #pragma unroll
    for(int r = 0; r < 8; r++) a1[r] = sb[r];
  }

  if(wg == 0 && lane == 0) out[NSTEP] = logp;
}

extern "C" void kernel_launch(void* const* d_in, const int* in_sizes, int n_in,
                              void* d_out, int out_size, void* d_ws, size_t ws_size,
                              hipStream_t stream){
  unsigned long long* h0buf = (unsigned long long*)d_ws;   // 512 slots
  unsigned long long* h1buf = h0buf + 512;                 // 512 slots
  hipLaunchKernelGGL(lstm_persist, dim3(NWG), dim3(BLK), 0, stream,
    (const float*)d_in[0],  (const float*)d_in[1],  (const float*)d_in[2],
    (const float*)d_in[3],  (const float*)d_in[4],  (const float*)d_in[5],  (const float*)d_in[6],
    (const float*)d_in[7],  (const float*)d_in[8],  (const float*)d_in[9],  (const float*)d_in[10],
    (const float*)d_in[11], (const float*)d_in[12],
    (float*)d_out, h0buf, h1buf);
}

// Round 9
// 32862.729 us; speedup vs baseline: 1.0700x; 1.0700x over previous
//
#include <hip/hip_runtime.h>
#include <stdint.h>
#include <math.h>

// Persistent barrier-free 2-layer LSTM rollout, MI355X (gfx950).
// v10 = EXACT v6 structure (best verified: 32.9ms) with the poll's spin
// loops converted from SERIAL dependent loads to 2-DEEP PIPELINED sampling:
//   Ledger (9 experiments): Lambda (~1.75us/hop) is insensitive to read
//   distribution (v8), rate below baseline (v9), walk order (v6~v1),
//   publish order (v5/v7). Remaining term: the spin's dependent-load chain
//   samples the slot once per RT (~1us coherent cross-XCD load). Detect =
//   1.5x RT. Fix: keep TWO staggered loads of the watched slot in flight
//   (no sleep, alternate regs) -> sampling period RT/2 -> detect ~1.25xRT/2
//   less. Applied to sentinel (phase 1) AND straggler walks (phase 3).
//   Wait-phase read rate rises ~2x (v8 proved 8x extra traffic is harmless;
//   only v3's 8x READ storm was toxic).
// Everything else byte-identical to v6. Numerics bit-identical to v1/v6.
//
// 512 WGs x 64 thr (1 wave); wave w owns h-units {2w, 2w+1} of both layers.
// Critical chain/step: poll h0 -> 8 gate rows -> publish h1 ->
//                      poll h1 -> W2 row -> cell0 -> publish h0.
// Whh0/Whh1 rows + threefry RNG run post-publish (shadow time).

#define H     1024
#define NSTEP 8192
#define NWG   512
#define BLK   64
#define NROW  25   // 0-7 Wih1 (4 gates x 2 units), 8-15 Whh0, 16-23 Whh1, 24 W2

typedef _Float16 h2 __attribute__((ext_vector_type(2)));
typedef _Float16 h8 __attribute__((ext_vector_type(8)));

union U32H2 { uint32_t u; h2 v; };

__device__ __forceinline__ unsigned long long pack_vt(float v0, float v1, uint32_t tag){
  U32H2 p; p.v.x = (_Float16)v0; p.v.y = (_Float16)v1;
  return ((unsigned long long)tag << 32) | (unsigned long long)p.u;
}

// Exact JAX threefry2x32.
__device__ __forceinline__ uint2 tf2x32(uint32_t k0, uint32_t k1, uint32_t x0, uint32_t x1){
  uint32_t k2 = k0 ^ k1 ^ 0x1BD11BDAu;
  x0 += k0; x1 += k1;
#define TFR(r) { x0 += x1; x1 = (x1 << (r)) | (x1 >> (32 - (r))); x1 ^= x0; }
  TFR(13) TFR(15) TFR(26) TFR(6)
  x0 += k1; x1 += k2 + 1u;
  TFR(17) TFR(29) TFR(16) TFR(24)
  x0 += k2; x1 += k0 + 2u;
  TFR(13) TFR(15) TFR(26) TFR(6)
  x0 += k0; x1 += k1 + 3u;
  TFR(17) TFR(29) TFR(16) TFR(24)
  x0 += k1; x1 += k2 + 4u;
  TFR(13) TFR(15) TFR(26) TFR(6)
  x0 += k2; x1 += k0 + 5u;
#undef TFR
  uint2 r; r.x = x0; r.y = x1; return r;
}

// keys = threefry_split(key(42), 8192)
__device__ __forceinline__ uint32_t jax_word(uint32_t i){
  return (i < 8192u) ? tf2x32(0u, 42u, i, i + 8192u).x
                     : tf2x32(0u, 42u, i - 8192u, i).y;
}

__device__ __forceinline__ float wred64(float x){
  #pragma unroll
  for(int off = 32; off > 0; off >>= 1) x += __shfl_xor(x, off, 64);
  return x;
}

#if __has_builtin(__builtin_amdgcn_fdot2)
__device__ __forceinline__ float fdot2f(h2 a, h2 b, float c){ return __builtin_amdgcn_fdot2(a, b, c, false); }
#else
__device__ __forceinline__ float fdot2f(h2 a, h2 b, float c){
  return (float)a.x * (float)b.x + (float)a.y * (float)b.y + c;
}
#endif

__device__ __forceinline__ float sigm(float x){
  x = fminf(fmaxf(x, -30.f), 30.f);
  return 1.f / (1.f + __expf(-x));
}
__device__ __forceinline__ float tanh_f(float x){
  x = fminf(fmaxf(x, -15.f), 15.f);
  float e = __expf(2.f * x);
  return (e - 1.f) / (e + 1.f);
}

__device__ __forceinline__ unsigned long long ld_slot(const unsigned long long* p){
  return __hip_atomic_load((unsigned long long*)p, __ATOMIC_RELAXED, __HIP_MEMORY_SCOPE_AGENT);
}

// 2-deep pipelined spin on one slot: two staggered loads in flight,
// alternate-check -> sampling period ~RT/2 (serial dependent chain = RT).
__device__ __forceinline__ unsigned long long spin2(const unsigned long long* p,
                                                    uint32_t tag,
                                                    unsigned long long init){
  if((uint32_t)(init >> 32) == tag) return init;
  unsigned long long a = ld_slot(p);
  unsigned long long b = ld_slot(p);
  while(true){
    if((uint32_t)(a >> 32) == tag) return a;
    a = ld_slot(p);
    if((uint32_t)(b >> 32) == tag) return b;
    b = ld_slot(p);
  }
}

// Poll this lane's 8 slots (fragment pairs [4l,4l+4) and [256+4l,+4)).
// phase 0: batched initial snapshot
// phase 1: 2-deep pipelined sentinel spin on slot 0
// phase 2: one batched concurrent reload of the stale remainder (~1 RT)
// phase 3: 2-deep pipelined walk for stragglers
__device__ __forceinline__ void poll_h(const unsigned long long* __restrict__ buf,
                                       uint32_t tag, int lane, h2* hv){
  const unsigned long long* p0 = buf + (lane << 2);
  const unsigned long long* p1 = buf + 256 + (lane << 2);
  unsigned long long pv[8];
  #pragma unroll
  for(int k = 0; k < 4; k++) pv[k]     = ld_slot(p0 + k);
  #pragma unroll
  for(int k = 0; k < 4; k++) pv[4 + k] = ld_slot(p1 + k);

  // phase 1: pipelined sentinel
  pv[0] = spin2(p0, tag, pv[0]);

  // phase 2: batched refresh of whatever is still stale
  bool any = false;
  #pragma unroll
  for(int k = 1; k < 8; k++) any |= ((uint32_t)(pv[k] >> 32) != tag);
  if(any){
    #pragma unroll
    for(int k = 1; k < 8; k++){
      if((uint32_t)(pv[k] >> 32) != tag){
        const unsigned long long* p = (k < 4) ? (p0 + k) : (p1 + (k - 4));
        pv[k] = ld_slot(p);
      }
    }
    // phase 3: stragglers — pipelined per-slot spin
    #pragma unroll
    for(int k = 1; k < 8; k++){
      const unsigned long long* p = (k < 4) ? (p0 + k) : (p1 + (k - 4));
      pv[k] = spin2(p, tag, pv[k]);
    }
  }

  #pragma unroll
  for(int k = 0; k < 8; k++){
    U32H2 u; u.u = (uint32_t)pv[k];
    hv[k] = u.v;
  }
}

// Row dot partial: lane l covers h2 [4l,4l+4) and [256+4l,+4): two b128
// LDS reads, lane stride 16B -> conflict-free.
__device__ __forceinline__ float row_part(const h2* __restrict__ wrow, int lane, const h2* hv){
  h8 wl = *(const h8*)(wrow + (lane << 2));
  h8 wh = *(const h8*)(wrow + 256 + (lane << 2));
  float a0 = 0.f, a1 = 0.f;
  h2 w;
  w = __builtin_shufflevector(wl, wl, 0, 1); a0 = fdot2f(w, hv[0], a0);
  w = __builtin_shufflevector(wl, wl, 2, 3); a1 = fdot2f(w, hv[1], a1);
  w = __builtin_shufflevector(wl, wl, 4, 5); a0 = fdot2f(w, hv[2], a0);
  w = __builtin_shufflevector(wl, wl, 6, 7); a1 = fdot2f(w, hv[3], a1);
  w = __builtin_shufflevector(wh, wh, 0, 1); a0 = fdot2f(w, hv[4], a0);
  w = __builtin_shufflevector(wh, wh, 2, 3); a1 = fdot2f(w, hv[5], a1);
  w = __builtin_shufflevector(wh, wh, 4, 5); a0 = fdot2f(w, hv[6], a0);
  w = __builtin_shufflevector(wh, wh, 6, 7); a1 = fdot2f(w, hv[7], a1);
  return a0 + a1;
}

__global__ void __launch_bounds__(BLK)
lstm_persist(const float* __restrict__ ctx,  const float* __restrict__ W1p,  const float* __restrict__ b1p,
             const float* __restrict__ Wih0, const float* __restrict__ Whh0,
             const float* __restrict__ bih0, const float* __restrict__ bhh0,
             const float* __restrict__ Wih1, const float* __restrict__ Whh1,
             const float* __restrict__ bih1, const float* __restrict__ bhh1,
             const float* __restrict__ W2p,  const float* __restrict__ b2p,
             float* __restrict__ out,
             unsigned long long* __restrict__ h0buf,
             unsigned long long* __restrict__ h1buf)
{
  __shared__ h2 w[NROW][H/2];   // 51.2 KB (<64KB/block cap); 2 WGs/CU

  const int lane = threadIdx.x;   // single wave per WG
  const int wg   = blockIdx.x;
  const int j0   = wg << 1;       // this wave's two h-units: j0, j0+1

  // ---- one-time: stage 25 rows as f16 (coalesced float4 reads)
  #pragma unroll 1
  for(int r = 0; r < NROW; r++){
    const float* rowp;
    if(r < 8)      { int g = r & 3,        j = j0 + (r >> 2);        rowp = Wih1 + (size_t)(g*H + j)*H; }
    else if(r < 16){ int rr = r - 8;  int g = rr & 3, j = j0 + (rr >> 2); rowp = Whh0 + (size_t)(g*H + j)*H; }
    else if(r < 24){ int rr = r - 16; int g = rr & 3, j = j0 + (rr >> 2); rowp = Whh1 + (size_t)(g*H + j)*H; }
    else           rowp = W2p;
    const float4* s4 = (const float4*)rowp;
    #pragma unroll
    for(int it = 0; it < 4; it++){
      float4 f = s4[lane + (it << 6)];
      h2 pa; pa.x = (_Float16)f.x; pa.y = (_Float16)f.y;
      h2 pb; pb.x = (_Float16)f.z; pb.y = (_Float16)f.w;
      const int ci = (lane + (it << 6)) << 1;
      w[r][ci] = pa; w[r][ci + 1] = pb;
    }
  }
  __syncthreads();

  // per-wave scalars for both units (uniform across lanes)
  float b0g[8], b1g[8], w0g[8];
  #pragma unroll
  for(int e = 0; e < 2; e++){
    const int j = j0 + e;
    #pragma unroll
    for(int g = 0; g < 4; g++){
      b0g[4*e + g] = bih0[g*H + j] + bhh0[g*H + j];
      b1g[4*e + g] = bih1[g*H + j] + bhh1[g*H + j];
      w0g[4*e + g] = Wih0[g*H + j];
    }
  }
  const float b2v = b2p[0];

  // x0 = W1 @ context + b1
  float xacc = 0.f;
  for(int c = lane; c < 512; c += 64) xacc += W1p[c] * ctx[c];
  const float x0 = wred64(xacc) + b1p[0];

  float c0[2], c1[2] = {0.f, 0.f}, logp = 0.f;
  float a0[8];
  float a1[8] = {0.f,0.f,0.f,0.f,0.f,0.f,0.f,0.f};

  // h0(0) from x0 for both units
  {
    float h0v[2];
    #pragma unroll
    for(int e = 0; e < 2; e++){
      float gi = sigm (w0g[4*e+0]*x0 + b0g[4*e+0]);
      float gg = tanh_f(w0g[4*e+2]*x0 + b0g[4*e+2]);
      float go = sigm (w0g[4*e+3]*x0 + b0g[4*e+3]);
      c0[e] = gi * gg;
      h0v[e] = go * tanh_f(c0[e]);
    }
    if(lane == 0)
      __hip_atomic_store(&h0buf[wg], pack_vt(h0v[0], h0v[1], 1u),
                         __ATOMIC_RELAXED, __HIP_MEMORY_SCOPE_AGENT);
  }

  h2 hv[8];
  float u = 0.f;

  #pragma unroll 1
  for(int t = 0; t < NSTEP; t++){
    const uint32_t tt = (uint32_t)t;

    // ================= P1: consume h0(t) =================
    poll_h(h0buf, tt + 1u, lane, hv);

    // critical: 8 layer-1 gate rows (Wih1, both units)
    float s1[8];
    #pragma unroll
    for(int r = 0; r < 8; r++) s1[r] = row_part(&w[r][0], lane, hv);
    #pragma unroll
    for(int off = 32; off > 0; off >>= 1){
      #pragma unroll
      for(int r = 0; r < 8; r++) s1[r] += __shfl_xor(s1[r], off, 64);
    }
    {
      float h1v[2];
      #pragma unroll
      for(int e = 0; e < 2; e++){
        float gi = sigm (s1[4*e+0] + a1[4*e+0] + b1g[4*e+0]);
        float gf = sigm (s1[4*e+1] + a1[4*e+1] + b1g[4*e+1]);
        float gg = tanh_f(s1[4*e+2] + a1[4*e+2] + b1g[4*e+2]);
        float go = sigm (s1[4*e+3] + a1[4*e+3] + b1g[4*e+3]);
        c1[e] = gf*c1[e] + gi*gg;
        h1v[e] = go * tanh_f(c1[e]);
      }
      if(lane == 0)
        __hip_atomic_store(&h1buf[wg], pack_vt(h1v[0], h1v[1], tt + 1u),
                           __ATOMIC_RELAXED, __HIP_MEMORY_SCOPE_AGENT);
    }

    // shadow: RNG + 8 Whh0 rows (a0 for P2's cell0)
    {
      const uint32_t kk0 = jax_word(2u*tt), kk1 = jax_word(2u*tt + 1u);
      const uint32_t bits = tf2x32(kk0, kk1, 0u, 0u).x;
      u = __uint_as_float((bits >> 9) | 0x3f800000u) - 1.0f;
    }
    float sa[8];
    #pragma unroll
    for(int r = 0; r < 8; r++) sa[r] = row_part(&w[8 + r][0], lane, hv);
    #pragma unroll
    for(int off = 32; off > 0; off >>= 1){
      #pragma unroll
      for(int r = 0; r < 8; r++) sa[r] += __shfl_xor(sa[r], off, 64);
    }
    #pragma unroll
    for(int r = 0; r < 8; r++) a0[r] = sa[r];

    // ================= P2: consume h1(t) =================
    poll_h(h1buf, tt + 1u, lane, hv);

    // critical: W2 row -> p,s -> cell0 -> publish h0(t+1)
    float z = row_part(&w[24][0], lane, hv);
    z = wred64(z) + b2v;
    const float p = sigm(z);
    const float s = (u < p) ? 1.f : 0.f;
    {
      float h0v[2];
      #pragma unroll
      for(int e = 0; e < 2; e++){
        float gi = sigm (a0[4*e+0] + w0g[4*e+0]*s + b0g[4*e+0]);
        float gf = sigm (a0[4*e+1] + w0g[4*e+1]*s + b0g[4*e+1]);
        float gg = tanh_f(a0[4*e+2] + w0g[4*e+2]*s + b0g[4*e+2]);
        float go = sigm (a0[4*e+3] + w0g[4*e+3]*s + b0g[4*e+3]);
        c0[e] = gf*c0[e] + gi*gg;
        h0v[e] = go * tanh_f(c0[e]);
      }
      if(lane == 0)
        __hip_atomic_store(&h0buf[wg], pack_vt(h0v[0], h0v[1], tt + 2u),
                           __ATOMIC_RELAXED, __HIP_MEMORY_SCOPE_AGENT);
    }

    // off critical path: logp/out after the publish
    logp += s * __logf(p) + (1.f - s) * __logf(1.f - p);
    if(wg == 0 && lane == 0) out[t] = s;

    // shadow: 8 Whh1 rows (a1 for next step's P1)
    float sb[8];
    #pragma unroll
    for(int r = 0; r < 8; r++) sb[r] = row_part(&w[16 + r][0], lane, hv);
    #pragma unroll
    for(int off = 32; off > 0; off >>= 1){
      #pragma unroll
      for(int r = 0; r < 8; r++) sb[r] += __shfl_xor(sb[r], off, 64);
    }
    #pragma unroll
    for(int r = 0; r < 8; r++) a1[r] = sb[r];
  }

  if(wg == 0 && lane == 0) out[NSTEP] = logp;
}

extern "C" void kernel_launch(void* const* d_in, const int* in_sizes, int n_in,
                              void* d_out, int out_size, void* d_ws, size_t ws_size,
                              hipStream_t stream){
  unsigned long long* h0buf = (unsigned long long*)d_ws;   // 512 slots
  unsigned long long* h1buf = h0buf + 512;                 // 512 slots
  hipLaunchKernelGGL(lstm_persist, dim3(NWG), dim3(BLK), 0, stream,
    (const float*)d_in[0],  (const float*)d_in[1],  (const float*)d_in[2],
    (const float*)d_in[3],  (const float*)d_in[4],  (const float*)d_in[5],  (const float*)d_in[6],
    (const float*)d_in[7],  (const float*)d_in[8],  (const float*)d_in[9],  (const float*)d_in[10],
    (const float*)d_in[11], (const float*)d_in[12],
    (float*)d_out, h0buf, h1buf);
}